// Round 7
// baseline (239.345 us; speedup 1.0000x reference)
//
#include <hip/hip_runtime.h>
#include <stdint.h>

// Simple exponential smoothing: level_t = (1-a)*level_{t-1} + a*y_t,
// level_0 = y_0 pinned via global initial carry s_{-1} = y_0.
// out[t] = level_t for t in [0, n-2].
//
// SINGLE-PASS kernel with a manual flat global barrier (regular launch;
// coop launch rejected under graph capture, R4). Input read once into
// registers, output written once via LDS-staged coalesced stores (R3).
//   phase 1: per-block affine reduce (input -> registers), publish aggregate
//   flat barrier: 2-level arrive (32 group counters -> root -> flag), t0 spins
//     - NOT R2's chained lookback (1023-deep serial coherence chain, ~80us);
//       one flat arrive + one flag observation per block.
//   phase 2: every block scans the G=1024 aggregates (8KB, L2) -> own carry
//   phase 3: replay from registers, 4-phase LDS-staged float4 stores
// Deadlock safety: grid=1024 blocks, footprint ~19KB LDS / ~80 VGPR ->
// HW capacity >= 8 blocks/CU = 2048 blocks >> 1024: all blocks co-resident.
//
// Affine pairs (a,b): s_out = a*s_in + b.
// combine(earlier=(a1,b1), later=(a2,b2)) = (a1*a2, a2*b1 + b2).

#define BLOCK 256
#define SEG   64                  // elements per thread
#define VPT   (SEG / 4)           // float4 per thread = 16
#define CHUNK (BLOCK * SEG)       // 16384 elements per block
#define ROWS  65                  // padded LDS row stride -> max 2-way bank alias (free)

// Inclusive Hillis-Steele scan over BLOCK affine pairs in LDS.
__device__ __forceinline__ void block_scan_affine(float* sa, float* sb, int t) {
#pragma unroll
    for (int off = 1; off < BLOCK; off <<= 1) {
        float pa = 1.0f, pb = 0.0f;
        if (t >= off) { pa = sa[t - off]; pb = sb[t - off]; }
        __syncthreads();
        if (t >= off) {
            float ca = sa[t], cb = sb[t];
            sa[t] = pa * ca;
            sb[t] = fmaf(ca, pb, cb);
        }
        __syncthreads();
    }
}

__global__ __launch_bounds__(BLOCK, 4) void k_ses_onepass(
    const float* __restrict__ y, const float* __restrict__ alpha_p,
    float* __restrict__ out,
    int* __restrict__ cnt,        // [32] group counters (ws, zeroed)
    int* __restrict__ root,       // [1]  root counter   (ws, zeroed)
    int* __restrict__ flag,       // [1]  release flag   (ws, zeroed)
    float2* __restrict__ agg,     // [G]  (a,b) per tile (ws, fully written)
    long n, int G)
{
    __shared__ float sa[BLOCK], sb[BLOCK];
    __shared__ float stage[64 * ROWS];      // 16640 B; ~19 KB total
    __shared__ float s_carry;

    const int t = threadIdx.x;
    const int tile = blockIdx.x;
    const float alpha = alpha_p[0];
    const float oma   = 1.0f - alpha;
    const long tbase = (long)tile * CHUNK;
    const long base  = tbase + (long)t * SEG;
    const bool fullTile = (tbase + CHUNK <= n);
    const float y0 = y[0];

    // ---- phase 1: load tile into registers, per-thread affine reduce ----
    float4 arr[VPT];
    float a_seg, b_seg;
    if (fullTile) {
        const float4* p = (const float4*)(y + base);
#pragma unroll
        for (int v = 0; v < VPT; ++v) arr[v] = p[v];
        float s = 0.0f;
#pragma unroll
        for (int v = 0; v < VPT; ++v) {
            s = fmaf(oma, s, alpha * arr[v].x);
            s = fmaf(oma, s, alpha * arr[v].y);
            s = fmaf(oma, s, alpha * arr[v].z);
            s = fmaf(oma, s, alpha * arr[v].w);
        }
        b_seg = s;
        a_seg = __powf(oma, (float)SEG);     // |err| ~ulp, irrelevant vs 2e-2 threshold
    } else {
        float a = 1.0f, s = 0.0f;
        for (int k = 0; k < SEG; ++k) {
            long idx = base + k;
            if (idx < n) { s = fmaf(oma, s, alpha * y[idx]); a *= oma; }
        }
        a_seg = a; b_seg = s;
    }

    sa[t] = a_seg; sb[t] = b_seg;
    __syncthreads();
    block_scan_affine(sa, sb, t);

    // per-thread exclusive prefix within tile (before sa/sb reuse in phase 2)
    float ea_th = 1.0f, eb_th = 0.0f;
    if (t > 0) { ea_th = sa[t - 1]; eb_th = sb[t - 1]; }

    // publish this tile's aggregate, then fence so arrival ordering holds
    if (t == BLOCK - 1) {
        float2 ab; ab.x = sa[t]; ab.y = sb[t];
        agg[tile] = ab;
        __threadfence();                      // device-scope: agg visible pre-arrive
    }
    __syncthreads();                          // order t255's store before t0's arrive

    // ---- flat global barrier ----
    if (t == 0) {
        const int grp   = tile >> 5;                          // 32 blocks/group
        const int gbase = grp << 5;
        const int gsz   = (G - gbase < 32) ? (G - gbase) : 32;
        const int ngrp  = (G + 31) >> 5;
        int old = __hip_atomic_fetch_add(&cnt[grp], 1, __ATOMIC_RELEASE, __HIP_MEMORY_SCOPE_AGENT);
        if (old == gsz - 1) {
            int old2 = __hip_atomic_fetch_add(root, 1, __ATOMIC_ACQ_REL, __HIP_MEMORY_SCOPE_AGENT);
            if (old2 == ngrp - 1) {
                __hip_atomic_store(flag, 1, __ATOMIC_RELEASE, __HIP_MEMORY_SCOPE_AGENT);
            }
        }
        while (__hip_atomic_load(flag, __ATOMIC_ACQUIRE, __HIP_MEMORY_SCOPE_AGENT) == 0) {
            __builtin_amdgcn_s_sleep(1);
        }
        __threadfence();
    }
    __syncthreads();                          // release whole block past barrier

    // ---- phase 2: scan all G aggregates -> this tile's carry ----
    const int items = (G + BLOCK - 1) / BLOCK;       // 4 for G=1024
    {
        float ta = 1.0f, tb = 0.0f;
        for (int j = 0; j < items; ++j) {
            int g = t * items + j;
            if (g < G) {
                float2 ab = agg[g];
                tb = fmaf(ab.x, tb, ab.y);
                ta *= ab.x;
            }
        }
        sa[t] = ta; sb[t] = tb;
        __syncthreads();
        block_scan_affine(sa, sb, t);

        const int q = tile / items;          // owning thread for this tile's prefix
        if (t == q) {
            float ea = (q > 0) ? sa[q - 1] : 1.0f;
            float eb = (q > 0) ? sb[q - 1] : 0.0f;
            const int r = tile - q * items;  // remaining aggregates [q*items, tile)
            for (int j = 0; j < r; ++j) {
                float2 ab = agg[q * items + j];
                eb = fmaf(ab.x, eb, ab.y);
                ea *= ab.x;
            }
            s_carry = fmaf(ea, y0, eb);      // level just before this tile
        }
        __syncthreads();
    }

    float lvl = fmaf(ea_th, s_carry, eb_th); // level just before this thread's segment

    // ---- phase 3: replay from registers, 4-phase staged coalesced output ----
    if (fullTile) {
#pragma unroll
        for (int v = 0; v < VPT; ++v) {
            float4 q4 = arr[v], r;
            lvl = fmaf(oma, lvl, alpha * q4.x); r.x = lvl;
            lvl = fmaf(oma, lvl, alpha * q4.y); r.y = lvl;
            lvl = fmaf(oma, lvl, alpha * q4.z); r.z = lvl;
            lvl = fmaf(oma, lvl, alpha * q4.w); r.w = lvl;
            arr[v] = r;
        }
        const int  wv = t >> 6;                    // wave id 0..3
        const int  ln = t & 63;
        const bool lastGuard = (tbase + CHUNK > n - 1);
#pragma unroll
        for (int p = 0; p < 4; ++p) {
            __syncthreads();                       // stage reuse barrier
            if (wv == p) {                         // wave p owns elems [p*4096,(p+1)*4096)
                float* row = &stage[ln * ROWS];
#pragma unroll
                for (int v = 0; v < VPT; ++v) {
                    row[4 * v + 0] = arr[v].x;
                    row[4 * v + 1] = arr[v].y;
                    row[4 * v + 2] = arr[v].z;
                    row[4 * v + 3] = arr[v].w;
                }
            }
            __syncthreads();
            const long rbase = tbase + (long)p * 4096;
#pragma unroll
            for (int k = 0; k < 4; ++k) {
                int jj = t + (k << 8);             // float4 idx 0..1023
                int g  = jj >> 4;                  // source row
                int e  = (jj << 2) & 63;           // col within row
                const float* row = &stage[g * ROWS + e];
                float4 r;
                r.x = row[0]; r.y = row[1]; r.z = row[2]; r.w = row[3];
                long gi = rbase + 4 * (long)jj;
                if (!lastGuard) {
                    *(float4*)(out + gi) = r;
                } else {
                    if (gi + 4 <= n - 1) {
                        *(float4*)(out + gi) = r;
                    } else {
                        if (gi + 0 < n - 1) out[gi + 0] = r.x;
                        if (gi + 1 < n - 1) out[gi + 1] = r.y;
                        if (gi + 2 < n - 1) out[gi + 2] = r.z;
                        if (gi + 3 < n - 1) out[gi + 3] = r.w;
                    }
                }
            }
        }
    } else {
        for (int k = 0; k < SEG; ++k) {
            long idx = base + k;
            if (idx < n) {
                lvl = fmaf(oma, lvl, alpha * y[idx]);
                if (idx < n - 1) out[idx] = lvl;
            }
        }
    }
}

extern "C" void kernel_launch(void* const* d_in, const int* in_sizes, int n_in,
                              void* d_out, int out_size, void* d_ws, size_t ws_size,
                              hipStream_t stream) {
    const float* y     = (const float*)d_in[0];
    const float* alpha = (const float*)d_in[1];
    float* out = (float*)d_out;
    const long n = (long)in_sizes[0];
    const int  G = (int)((n + CHUNK - 1) / CHUNK);   // 1024 for n = 2^24

    // ws layout: [0,128) cnt[32] | [256,260) root | [384,388) flag |
    //            [512, 512+8G) agg[G] float2
    char* ws = (char*)d_ws;
    int*    cnt  = (int*)ws;
    int*    root = (int*)(ws + 256);
    int*    flg  = (int*)(ws + 384);
    float2* agg  = (float2*)(ws + 512);

    hipMemsetAsync(d_ws, 0, 512, stream);    // zero barrier state (ws is poisoned)
    k_ses_onepass<<<G, BLOCK, 0, stream>>>(y, alpha, out, cnt, root, flg, agg, n, G);
}

// Round 8
// 126.586 us; speedup vs baseline: 1.8908x; 1.8908x over previous
//
#include <hip/hip_runtime.h>
#include <stdint.h>

// Simple exponential smoothing: level_t = (1-a)*level_{t-1} + a*y_t,
// level_0 = y_0 pinned via global initial carry s_{-1} = y_0.
// out[t] = level_t for t in [0, n-2].
//
// 2-pass reduce-then-scan (R5 structure, best measured = 129.2us):
//   pass 1: per-block affine aggregate -> aggA/aggB[G]
//   pass 2 (fused): each block redundantly scans the G aggregates (8KB, L2)
//           to get its own carry, then replays its tile from register-cached
//           input and emits via LDS-staged coalesced stores.
// R8 deltas vs R5: NON-TEMPORAL output stores (output never re-read; avoid
// 66MB of L2/L3 write-allocate churn that evicts the L3-warm input during
// emit) + __powf -> 6 squarings.
// Bans (measured): in-kernel grid sync (R2 lookback ~80us, R7 flat barrier
// ~125us — cross-XCD coherence), coop launch (R4: graph-capture reject).
//
// Affine pairs (a,b): s_out = a*s_in + b.
// combine(earlier=(a1,b1), later=(a2,b2)) = (a1*a2, a2*b1 + b2).

#define BLOCK 256
#define SEG   64                  // elements per thread
#define VPT   (SEG / 4)           // float4 per thread
#define CHUNK (BLOCK * SEG)       // 16384 elements per block
#define ROWS  65                  // padded LDS row stride -> max 2-way bank alias
                                  // (conflict-free measured: 512 cyc/block, R2)

typedef float f32x4 __attribute__((ext_vector_type(4)));

__device__ __forceinline__ void nt_store4(float* p, float x, float y, float z, float w) {
    f32x4 v = {x, y, z, w};
    __builtin_nontemporal_store(v, (f32x4*)p);
}

// oma^SEG via repeated squaring (SEG=64 = 2^6)
__device__ __forceinline__ float pow_seg(float oma) {
    float p = oma;
#pragma unroll
    for (int i = 0; i < 6; ++i) p *= p;
    return p;
}

// Inclusive Hillis-Steele scan over BLOCK affine pairs in LDS.
__device__ __forceinline__ void block_scan_affine(float* sa, float* sb, int t) {
#pragma unroll
    for (int off = 1; off < BLOCK; off <<= 1) {
        float pa = 1.0f, pb = 0.0f;
        if (t >= off) { pa = sa[t - off]; pb = sb[t - off]; }
        __syncthreads();
        if (t >= off) {
            float ca = sa[t], cb = sb[t];
            sa[t] = pa * ca;
            sb[t] = fmaf(ca, pb, cb);
        }
        __syncthreads();
    }
}

// Pass 1: per-block affine aggregate.
__global__ __launch_bounds__(BLOCK) void k_block_agg(
    const float* __restrict__ y, const float* __restrict__ alpha_p,
    float* __restrict__ aggA, float* __restrict__ aggB, long n)
{
    const int t = threadIdx.x;
    const long base = (long)blockIdx.x * CHUNK + (long)t * SEG;
    const float alpha = alpha_p[0];
    const float oma = 1.0f - alpha;

    float a = 1.0f, s = 0.0f;
    if (base + SEG <= n) {
        const float4* p = (const float4*)(y + base);
#pragma unroll
        for (int v = 0; v < VPT; ++v) {
            float4 q = p[v];
            s = fmaf(oma, s, alpha * q.x);
            s = fmaf(oma, s, alpha * q.y);
            s = fmaf(oma, s, alpha * q.z);
            s = fmaf(oma, s, alpha * q.w);
        }
        a = pow_seg(oma);
    } else {
        for (int k = 0; k < SEG; ++k) {
            long idx = base + k;
            if (idx < n) { s = fmaf(oma, s, alpha * y[idx]); a *= oma; }
        }
    }

    __shared__ float sa[BLOCK], sb[BLOCK];
    sa[t] = a; sb[t] = s;
    __syncthreads();
    block_scan_affine(sa, sb, t);
    if (t == BLOCK - 1) {
        aggA[blockIdx.x] = sa[t];
        aggB[blockIdx.x] = sb[t];
    }
}

// Pass 2 (fused): per-block carry from redundant aggregate scan, then replay
// from register-cached input and emit via LDS-staged coalesced NT stores.
__global__ __launch_bounds__(BLOCK, 4) void k_emit_fused(
    const float* __restrict__ y, const float* __restrict__ alpha_p,
    const float* __restrict__ aggA, const float* __restrict__ aggB,
    float* __restrict__ out, long n, int G)
{
    __shared__ float sa[BLOCK], sb[BLOCK];
    __shared__ float stage[2 * 64 * ROWS];   // 33280 B; ~35.4 KB total -> 4 blocks/CU
    __shared__ float s_carry;

    const int t = threadIdx.x;
    const int tile = blockIdx.x;
    const float alpha = alpha_p[0];
    const float oma   = 1.0f - alpha;
    const long tbase = (long)tile * CHUNK;
    const long base  = tbase + (long)t * SEG;
    const bool fullTile = (tbase + CHUNK <= n);
    const float y0 = y[0];

    // ---- phase A: load tile into registers, per-thread affine reduce ----
    float4 arr[VPT];
    float a_seg, b_seg;
    if (fullTile) {
        const float4* p = (const float4*)(y + base);
#pragma unroll
        for (int v = 0; v < VPT; ++v) arr[v] = p[v];
        float s = 0.0f;
#pragma unroll
        for (int v = 0; v < VPT; ++v) {
            s = fmaf(oma, s, alpha * arr[v].x);
            s = fmaf(oma, s, alpha * arr[v].y);
            s = fmaf(oma, s, alpha * arr[v].z);
            s = fmaf(oma, s, alpha * arr[v].w);
        }
        b_seg = s;
        a_seg = pow_seg(oma);
    } else {
        float a = 1.0f, s = 0.0f;
        for (int k = 0; k < SEG; ++k) {
            long idx = base + k;
            if (idx < n) { s = fmaf(oma, s, alpha * y[idx]); a *= oma; }
        }
        a_seg = a; b_seg = s;
    }

    sa[t] = a_seg; sb[t] = b_seg;
    __syncthreads();
    block_scan_affine(sa, sb, t);

    // per-thread exclusive prefix within tile (before sa/sb are reused)
    float ea_th = 1.0f, eb_th = 0.0f;
    if (t > 0) { ea_th = sa[t - 1]; eb_th = sb[t - 1]; }

    // ---- phase B: redundant scan of G aggregates -> this tile's carry ----
    const int items = (G + BLOCK - 1) / BLOCK;       // 4 for G=1024
    {
        float ta = 1.0f, tb = 0.0f;
        for (int j = 0; j < items; ++j) {
            int g = t * items + j;
            if (g < G) {
                float ca = aggA[g], cb = aggB[g];
                tb = fmaf(ca, tb, cb);
                ta *= ca;
            }
        }
        __syncthreads();             // ea_th/eb_th reads done; safe to reuse sa/sb
        sa[t] = ta; sb[t] = tb;
        __syncthreads();
        block_scan_affine(sa, sb, t);

        const int q = tile / items;          // owning thread for this tile's prefix
        if (t == q) {
            float ea = (q > 0) ? sa[q - 1] : 1.0f;
            float eb = (q > 0) ? sb[q - 1] : 0.0f;
            const int r = tile - q * items;  // remaining aggregates [q*items, tile)
            for (int j = 0; j < r; ++j) {
                int g = q * items + j;
                float ca = aggA[g], cb = aggB[g];
                eb = fmaf(ca, eb, cb);
                ea *= ca;
            }
            s_carry = fmaf(ea, y0, eb);      // level just before this tile
        }
        __syncthreads();
    }

    float lvl = fmaf(ea_th, s_carry, eb_th); // level just before this thread's segment

    // ---- phase C: replay from registers, staged coalesced NT output ----
    if (fullTile) {
#pragma unroll
        for (int v = 0; v < VPT; ++v) {
            float4 q4 = arr[v], r;
            lvl = fmaf(oma, lvl, alpha * q4.x); r.x = lvl;
            lvl = fmaf(oma, lvl, alpha * q4.y); r.y = lvl;
            lvl = fmaf(oma, lvl, alpha * q4.z); r.z = lvl;
            lvl = fmaf(oma, lvl, alpha * q4.w); r.w = lvl;
            arr[v] = r;
        }
        const int  wv = t >> 6;
        const int  ln = t & 63;
        const bool lastGuard = (tbase + CHUNK > n - 1);
#pragma unroll
        for (int p = 0; p < 2; ++p) {
            __syncthreads();                       // stage reuse barrier
            if ((wv >> 1) == p) {
                int g = ((wv & 1) << 6) | ln;      // row 0..127 within phase
                float* row = &stage[g * ROWS];
#pragma unroll
                for (int v = 0; v < VPT; ++v) {
                    row[4 * v + 0] = arr[v].x;
                    row[4 * v + 1] = arr[v].y;
                    row[4 * v + 2] = arr[v].z;
                    row[4 * v + 3] = arr[v].w;
                }
            }
            __syncthreads();
            const long rbase = tbase + (long)p * 8192;
#pragma unroll
            for (int k = 0; k < 8; ++k) {
                int jj = t + (k << 8);             // float4 idx 0..2047
                int g  = jj >> 4;
                int e  = (jj << 2) & 63;
                const float* row = &stage[g * ROWS + e];
                float rx = row[0], ry = row[1], rz = row[2], rw = row[3];
                long gi = rbase + 4 * (long)jj;
                if (!lastGuard) {
                    nt_store4(out + gi, rx, ry, rz, rw);
                } else {
                    if (gi + 4 <= n - 1) {
                        nt_store4(out + gi, rx, ry, rz, rw);
                    } else {
                        if (gi + 0 < n - 1) out[gi + 0] = rx;
                        if (gi + 1 < n - 1) out[gi + 1] = ry;
                        if (gi + 2 < n - 1) out[gi + 2] = rz;
                        if (gi + 3 < n - 1) out[gi + 3] = rw;
                    }
                }
            }
        }
    } else {
        for (int k = 0; k < SEG; ++k) {
            long idx = base + k;
            if (idx < n) {
                lvl = fmaf(oma, lvl, alpha * y[idx]);
                if (idx < n - 1) out[idx] = lvl;
            }
        }
    }
}

extern "C" void kernel_launch(void* const* d_in, const int* in_sizes, int n_in,
                              void* d_out, int out_size, void* d_ws, size_t ws_size,
                              hipStream_t stream) {
    const float* y     = (const float*)d_in[0];
    const float* alpha = (const float*)d_in[1];
    float* out = (float*)d_out;
    const long n = (long)in_sizes[0];
    const int  G = (int)((n + CHUNK - 1) / CHUNK);   // 1024 for n = 2^24

    float* aggA = (float*)d_ws;        // G floats
    float* aggB = aggA + G;            // G floats (fully written before read; no zeroing)

    k_block_agg<<<G, BLOCK, 0, stream>>>(y, alpha, aggA, aggB, n);
    k_emit_fused<<<G, BLOCK, 0, stream>>>(y, alpha, aggA, aggB, out, n, G);
}